// Round 11
// baseline (34946.552 us; speedup 1.0000x reference)
//
#include <hip/hip_runtime.h>
#include <stdint.h>

#define T_N   128
#define B_N   64
#define OBS   32
#define C_N   33      // OBS+1
#define HID   64
#define WID   128
#define FOUT  2112    // HID*C_N
#define OUTD  32
#define NSUB  4
#define NTH   1024

// d_ws: MFMA A-fragment planes for fWo (round-9 layout, proven).
// plane p = t*4+kb (t=tile of 16 rows, kb=K-block of 32), 64 lanes x 16B:
//   lane holds W[16t+(lane&15)][kb*32+(lane>>4)*8 + j], j=0..7 (bf16 pairs)
#define NTILE_T  132                   // 2112/16
#define NPLANES  (NTILE_T*4)           // 528
#define WS_NEED  ((size_t)NPLANES * 64 * 16)   // 540672 B

typedef __attribute__((ext_vector_type(8))) short  bf16x8;
typedef __attribute__((ext_vector_type(4))) float  f32x4;

__device__ __forceinline__ float b2f(unsigned short u) {
    return __uint_as_float(((unsigned int)u) << 16);
}
__device__ __forceinline__ float b2f_lo(unsigned int u) {
    return __uint_as_float(u << 16);
}
__device__ __forceinline__ float b2f_hi(unsigned int u) {
    return __uint_as_float(u & 0xffff0000u);
}
__device__ __forceinline__ unsigned short f2b(float f) {
    unsigned int u = __float_as_uint(f);
    unsigned int lsb = (u >> 16) & 1u;
    u += 0x7fffu + lsb;   // round to nearest even
    return (unsigned short)(u >> 16);
}
__device__ __forceinline__ unsigned int pack2(float a, float b) {
    return ((unsigned int)f2b(a)) | (((unsigned int)f2b(b)) << 16);
}
// packed truncation-hi of two f32 (exact upper bf16 halves)
__device__ __forceinline__ unsigned int pkhi(float a, float b) {
    return (__float_as_uint(a) >> 16) | (__float_as_uint(b) & 0xffff0000u);
}
// packed bf16(residual) of two f32
__device__ __forceinline__ unsigned int pklo(float a, float b) {
    float la = a - __uint_as_float(__float_as_uint(a) & 0xffff0000u);
    float lb = b - __uint_as_float(__float_as_uint(b) & 0xffff0000u);
    return pack2(la, lb);
}
__device__ __forceinline__ bf16x8 u4b8(uint4 u) {
    union { uint4 a; bf16x8 b; } x; x.a = u; return x.b;
}
__device__ __forceinline__ float softplus_f(float x) {
    return fmaxf(x, 0.f) + __logf(1.f + __expf(-fabsf(x)));
}
__device__ __forceinline__ float tanh_fast(float x) {
    float e = __expf(2.f * x);
    return 1.f - 2.f / (e + 1.f);
}

// ---- dtype policies -------------------------------------------------------
struct PolBF16 {
    static __device__ __forceinline__ float ld(const void* p, int i) {
        return b2f(((const unsigned short*)p)[i]);
    }
    static __device__ __forceinline__ void ld8(const void* p, int i, float* o) {
        uint4 u = *(const uint4*)((const unsigned short*)p + i);
        o[0]=b2f_lo(u.x); o[1]=b2f_hi(u.x); o[2]=b2f_lo(u.y); o[3]=b2f_hi(u.y);
        o[4]=b2f_lo(u.z); o[5]=b2f_hi(u.z); o[6]=b2f_lo(u.w); o[7]=b2f_hi(u.w);
    }
    static __device__ __forceinline__ void st(void* p, int i, float v) {
        ((unsigned short*)p)[i] = f2b(v);
    }
};
struct PolF32 {
    static __device__ __forceinline__ float ld(const void* p, int i) {
        return ((const float*)p)[i];
    }
    static __device__ __forceinline__ void ld8(const void* p, int i, float* o) {
        const float4* q = (const float4*)((const float*)p + i);
        float4 a = q[0], b = q[1];
        o[0]=a.x; o[1]=a.y; o[2]=a.z; o[3]=a.w;
        o[4]=b.x; o[5]=b.y; o[6]=b.z; o[7]=b.w;
    }
    static __device__ __forceinline__ void st(void* p, int i, float v) {
        ((float*)p)[i] = v;
    }
};

struct __align__(16) Smem {
    uint4 whf[3][32][64];            // 96 KB : hidden A-fragments [l][t*4+kb]
    uint4 w0f[16][64];               // 16 KB : layer0 A-fragments [t*2+kb]
    float rowp[2][FOUT];             // 16.5 KB : output partials / init scratch
    unsigned int hpk[2][2][64];      // 1 KB : packed h (buf, hi/lo, 64 pairs)
    unsigned int ypk[2][32];         // 256 B : packed y (hi/lo, 32 pairs)
    float y[HID];
    float yt[HID];
    float xd[C_N], d0[C_N], cc[C_N], bb[C_N];
    float fb0[WID];
    float fbh[3][WID];
    float lWt[HID*OUTD];             // transposed [k][o]
};  // ~144 KB

// ---- weight prep: fWo -> MFMA A-fragment planes in d_ws (round-9 layout) --
template<class P>
__device__ __forceinline__ void prep_body(const void* fWo, unsigned short* ws) {
    const int e    = blockIdx.x * NTH + threadIdx.x;   // 0..33791
    const int p    = e >> 6;                           // plane 0..527
    const int lane = e & 63;
    const int t    = p >> 2;
    const int kb   = p & 3;
    const int row  = 16*t + (lane & 15);
    const int k0   = kb*32 + ((lane >> 4) << 3);
    float v[8];
    P::ld8(fWo, row*WID + k0, v);
    uint4 u;
    u.x = pack2(v[0],v[1]); u.y = pack2(v[2],v[3]);
    u.z = pack2(v[4],v[5]); u.w = pack2(v[6],v[7]);
    ((uint4*)ws)[e] = u;
}
__global__ __launch_bounds__(NTH)
void prep_kernel(const void* ts, const void* fWo, unsigned short* ws) {
    const bool isbf = (((const unsigned short*)ts)[1] == 0x3C00);
    if (isbf) prep_body<PolBF16>(fWo, ws);
    else      prep_body<PolF32>(fWo, ws);
}

// ---- main persistent-per-batch kernel -------------------------------------
template<class P, bool COAL>
__device__ void run_cde(
    const void* ts, const void* ys, const void* iW0, const void* ib0,
    const void* iWh, const void* ibh, const void* iWo, const void* ibo,
    const void* fW0, const void* fb0, const void* fWh, const void* fbh,
    const void* fWo, const void* fbo, const void* lW, const void* lb,
    const void* wWo, void* out, Smem& S)
{
    const int tid  = threadIdx.x;
    const int b    = blockIdx.x;
    const int g16  = tid >> 4;       // 0..63  : output group == h index
    const int l16  = tid & 15;       // 0..15  : lane within group
    const int r0   = g16*C_N + l16;        // output row (c = l16)
    const int r1   = r0 + 16;              // output row (c = 16+l16)
    const int rx   = g16*C_N + 32;         // shared row (c = 32)
    // MFMA wave geometry
    const int wv   = tid >> 6;       // wave 0..15
    const int lane = tid & 63;
    const int cidx = lane & 15;      // MFMA column index
    const int lg   = lane >> 4;      // 0..3
    const int pr   = wv & 7;         // output tile-residue class
    const int role = wv >> 3;        // output K-half role

    // ---- build A-fragments in LDS (once) ----
    {   // layer0: 16 planes (t*2+kb), one entry per thread
        const int p = tid >> 6;                 // 0..15
        const int t = p >> 1, kb = p & 1;
        const int row = 16*t + cidx;
        const int k0  = kb*32 + lg*8;
        uint4 u;
        u.x = pack2(P::ld(fW0, row*HID + k0+0), P::ld(fW0, row*HID + k0+1));
        u.y = pack2(P::ld(fW0, row*HID + k0+2), P::ld(fW0, row*HID + k0+3));
        u.z = pack2(P::ld(fW0, row*HID + k0+4), P::ld(fW0, row*HID + k0+5));
        u.w = pack2(P::ld(fW0, row*HID + k0+6), P::ld(fW0, row*HID + k0+7));
        S.w0f[p][lane] = u;
    }
    // hidden: 96 planes, 6 entries per thread
    #pragma unroll
    for (int i = 0; i < 6; ++i) {
        const int E = i*NTH + tid;
        const int p = E >> 6;                   // 0..95
        const int ln = E & 63;
        const int l = p >> 5, rem = p & 31;
        const int t = rem >> 2, kb = rem & 3;
        const int row = 16*t + (ln & 15);
        const int k0  = kb*32 + ((ln >> 4) << 3);
        const int base = (l*WID + row)*WID + k0;
        uint4 u;
        u.x = pack2(P::ld(fWh, base+0), P::ld(fWh, base+1));
        u.y = pack2(P::ld(fWh, base+2), P::ld(fWh, base+3));
        u.z = pack2(P::ld(fWh, base+4), P::ld(fWh, base+5));
        u.w = pack2(P::ld(fWh, base+6), P::ld(fWh, base+7));
        S.whf[l][rem][ln] = u;
    }

    const float fb_r0 = P::ld(fbo, r0);
    const float fb_r1 = P::ld(fbo, r1);
    const float fb_rx = P::ld(fbo, rx);

    // ---- constants to LDS ----
    if (tid < WID)  S.fb0[tid] = P::ld(fb0, tid);
    if (tid < 3*WID) S.fbh[tid>>7][tid&127] = P::ld(fbh, tid);
    for (int i = tid; i < OUTD*HID; i += NTH) {
        int o = i >> 6, kk = i & 63;             // lW is [o][k]
        S.lWt[kk*OUTD + o] = P::ld(lW, i);
    }
    if (tid < C_N)
        S.xd[tid] = (tid == 0) ? P::ld(ts, 0) : P::ld(ys, b*T_N*OBS + (tid-1));
    __syncthreads();

    // ---- initial MLP (relu hidden, identity out); scratch in rowp ----
    if (tid < WID) {
        float a = P::ld(ib0, tid);
        for (int k2 = 0; k2 < C_N; ++k2) a += P::ld(iW0, tid*C_N + k2) * S.xd[k2];
        S.rowp[0][tid] = fmaxf(a, 0.f);
    }
    __syncthreads();
    int pp = 0;
    for (int l = 0; l < 3; ++l) {
        if (tid < WID) {
            float a = P::ld(ibh, l*WID + tid);
            for (int k2 = 0; k2 < WID; ++k2)
                a += P::ld(iWh, (l*WID + tid)*WID + k2) * S.rowp[pp][k2];
            S.rowp[1-pp][tid] = fmaxf(a, 0.f);
        }
        __syncthreads();
        pp ^= 1;
    }
    if (tid < HID) {
        float a = P::ld(ibo, tid);
        for (int k2 = 0; k2 < WID; ++k2)
            a += P::ld(iWo, tid*WID + k2) * S.rowp[pp][k2];
        S.y[tid] = a;
    }
    __syncthreads();
    if (tid < OUTD) {
        float a = P::ld(lb, tid);
        for (int k2 = 0; k2 < HID; ++k2) a += S.lWt[k2*OUTD + tid] * S.y[k2];
        P::st(out, b*T_N*OUTD + tid, a);
    }

    // ---- sequential intervals ----
    #pragma unroll 1
    for (int iv = 0; iv < T_N-1; ++iv) {
        float t0 = P::ld(ts, iv), t1 = P::ld(ts, iv+1);
        float dt = t1 - t0;
        float hs = dt * (1.f/NSUB);
        if (tid < C_N) {
            float v0 = (tid==0) ? t0 : P::ld(ys, b*T_N*OBS + iv*OBS + (tid-1));
            float v1 = (tid==0) ? t1 : P::ld(ys, b*T_N*OBS + (iv+1)*OBS + (tid-1));
            float di = (v1 - v0) / dt;
            float d0v;
            if (iv == 0) d0v = di;
            else {
                float tm = P::ld(ts, iv-1);
                float vm = (tid==0) ? tm : P::ld(ys, b*T_N*OBS + (iv-1)*OBS + (tid-1));
                d0v = (v0 - vm) / (t0 - tm);
            }
            float d1v = di;
            S.d0[tid] = d0v;
            S.cc[tid] = (3.f*di - 2.f*d0v - d1v) / dt;
            S.bb[tid] = (d0v + d1v - 2.f*di) / (dt*dt);
        }
        __syncthreads();

        #pragma unroll 1
        for (int sub = 0; sub < NSUB; ++sub) {
            float s0 = sub * hs;
            float ka = 0.f, kb2 = 0.f, kc = 0.f;     // RK stage sums (l16==0)
            #pragma unroll 1
            for (int st = 0; st < 4; ++st) {
                float s = (st==0) ? s0 : ((st==3) ? s0+hs : s0 + 0.5f*hs);
                const float* yin = (st==0) ? S.y : S.yt;

                // ================= single-wave MLP (no barriers) ==========
                if (wv == 0) {
                    // pack y (hi/lo) into ypk — wave-internal
                    if (lane < 32) {
                        float v0 = yin[2*lane], v1 = yin[2*lane+1];
                        S.ypk[0][lane] = pkhi(v0, v1);
                        S.ypk[1][lane] = pklo(v0, v1);
                    }
                    // ---- layer 0: K=64, 8 tiles in 2 batches of 4 ----
                    {
                        const unsigned int* yb = (cidx == 1) ? S.ypk[1]
                                                             : S.ypk[0];
                        uint4 b0 = *(const uint4*)(yb + lg*4);
                        uint4 b1 = *(const uint4*)(yb + 16 + lg*4);
                        #pragma unroll
                        for (int half = 0; half < 2; ++half) {
                            f32x4 acc[4];
                            #pragma unroll
                            for (int tt = 0; tt < 4; ++tt) {
                                const int t = half*4 + tt;
                                uint4 a0 = S.w0f[t*2+0][lane];
                                uint4 a1 = S.w0f[t*2+1][lane];
                                f32x4 z = {0.f,0.f,0.f,0.f};
                                z = __builtin_amdgcn_mfma_f32_16x16x32_bf16(
                                        u4b8(a0), u4b8(b0), z, 0, 0, 0);
                                z = __builtin_amdgcn_mfma_f32_16x16x32_bf16(
                                        u4b8(a1), u4b8(b1), z, 0, 0, 0);
                                acc[tt] = z;
                            }
                            #pragma unroll
                            for (int tt = 0; tt < 4; ++tt) {
                                #pragma unroll
                                for (int r = 0; r < 4; ++r)
                                    acc[tt][r] += __shfl_xor(acc[tt][r], 1);
                                if (cidx == 0) {
                                    const int t = half*4 + tt;
                                    const int rb = 16*t + lg*4;
                                    float h0 = softplus_f(acc[tt][0] + S.fb0[rb+0]);
                                    float h1 = softplus_f(acc[tt][1] + S.fb0[rb+1]);
                                    float h2 = softplus_f(acc[tt][2] + S.fb0[rb+2]);
                                    float h3 = softplus_f(acc[tt][3] + S.fb0[rb+3]);
                                    const int o = 8*t + 2*lg;
                                    S.hpk[0][0][o]   = pkhi(h0,h1);
                                    S.hpk[0][0][o+1] = pkhi(h2,h3);
                                    S.hpk[0][1][o]   = pklo(h0,h1);
                                    S.hpk[0][1][o+1] = pklo(h2,h3);
                                }
                            }
                        }
                    }
                    // ---- 3 hidden layers: K=128, 8 tiles each ----
                    #pragma unroll
                    for (int l = 0; l < 3; ++l) {
                        const int ib = l & 1;
                        const unsigned int* hb = S.hpk[ib][(cidx==1) ? 1 : 0];
                        uint4 b0 = *(const uint4*)(hb + lg*4);
                        uint4 b1 = *(const uint4*)(hb + 16 + lg*4);
                        uint4 b2 = *(const uint4*)(hb + 32 + lg*4);
                        uint4 b3 = *(const uint4*)(hb + 48 + lg*4);
                        #pragma unroll
                        for (int half = 0; half < 2; ++half) {
                            f32x4 acc[4];
                            #pragma unroll
                            for (int tt = 0; tt < 4; ++tt) {
                                const int t = half*4 + tt;
                                uint4 a0 = S.whf[l][t*4+0][lane];
                                uint4 a1 = S.whf[l][t*4+1][lane];
                                uint4 a2 = S.whf[l][t*4+2][lane];
                                uint4 a3 = S.whf[l][t*4+3][lane];
                                f32x4 z = {0.f,0.f,0.f,0.f};
                                z = __builtin_amdgcn_mfma_f32_16x16x32_bf16(
                                        u4b8(a0), u4b8(b0), z, 0, 0, 0);
                                z = __builtin_amdgcn_mfma_f32_16x16x32_bf16(
                                        u4b8(a1), u4b8(b1), z, 0, 0, 0);
                                z = __builtin_amdgcn_mfma_f32_16x16x32_bf16(
                                        u4b8(a2), u4b8(b2), z, 0, 0, 0);
                                z = __builtin_amdgcn_mfma_f32_16x16x32_bf16(
                                        u4b8(a3), u4b8(b3), z, 0, 0, 0);
                                acc[tt] = z;
                            }
                            #pragma unroll
                            for (int tt = 0; tt < 4; ++tt) {
                                #pragma unroll
                                for (int r = 0; r < 4; ++r)
                                    acc[tt][r] += __shfl_xor(acc[tt][r], 1);
                                if (cidx == 0) {
                                    const int t = half*4 + tt;
                                    const int rb = 16*t + lg*4;
                                    float h0 = softplus_f(acc[tt][0] + S.fbh[l][rb+0]);
                                    float h1 = softplus_f(acc[tt][1] + S.fbh[l][rb+1]);
                                    float h2 = softplus_f(acc[tt][2] + S.fbh[l][rb+2]);
                                    float h3 = softplus_f(acc[tt][3] + S.fbh[l][rb+3]);
                                    const int o = 8*t + 2*lg;
                                    unsigned int* dhi = S.hpk[1-ib][0];
                                    unsigned int* dlo = S.hpk[1-ib][1];
                                    dhi[o]   = pkhi(h0,h1);
                                    dhi[o+1] = pkhi(h2,h3);
                                    dlo[o]   = pklo(h0,h1);
                                    dlo[o+1] = pklo(h2,h3);
                                }
                            }
                        }
                    }
                } else if (tid >= 64 && tid < 64 + C_N) {
                    // xdot(s), overlapped with wave-0 MLP
                    int c = tid - 64;
                    S.xd[c] = S.d0[c] + (2.f*S.cc[c] + 3.f*S.bb[c]*s)*s;
                }

                // ---- output stream prefetch (depth 4), all waves ----
                const uint4* ap = (const uint4*)wWo + (pr*4 + 2*role)*64 + lane;
                uint4 pa0, pa1, pa2, pa3;
                const uint4* ap2 = ap + 2048;
                if constexpr (COAL) {
                    pa0 = ap[0]; pa1 = ap[64];
                    pa2 = ap2[0]; pa3 = ap2[64];
                }
                __syncthreads();                                   // B_mid

                // ================= output layer =================
                if constexpr (COAL) {
                    const unsigned int* hb = S.hpk[1][(cidx==1) ? 1 : 0];
                    uint4 b0 = *(const uint4*)(hb + (2*role)*16 + lg*4);
                    uint4 b1 = *(const uint4*)(hb + (2*role+1)*16 + lg*4);
                    bf16x8 vb0 = u4b8(b0), vb1 = u4b8(b1);
                    const int ntile = (pr < 4) ? 17 : 16;
                    uint4 a0 = pa0, a1 = pa1, a2 = pa2, a3 = pa3;
                    int t = pr;
                    #pragma unroll 1
                    for (int i = 0; i < ntile; ++i) {
                        uint4 c0 = a0, c1 = a1;
                        a0 = a2; a1 = a3;
                        if (i + 2 < ntile) {
                            ap2 += 2048;
                            a2 = ap2[0]; a3 = ap2[64];
                        }
                        f32x4 acc = {0.f,0.f,0.f,0.f};
                        acc = __builtin_amdgcn_mfma_f32_16x16x32_bf16(
                                  u4b8(c0), vb0, acc, 0, 0, 0);
                        acc = __builtin_amdgcn_mfma_f32_16x16x32_bf16(
                                  u4b8(c1), vb1, acc, 0, 0, 0);
                        #pragma unroll
                        for (int r = 0; r < 4; ++r) acc[r] += __shfl_xor(acc[r], 1);
                        if (cidx == 0) {
                            float4 st4;
                            st4.x = acc[0]; st4.y = acc[1];
                            st4.z = acc[2]; st4.w = acc[3];
                            *(float4*)&S.rowp[role][16*t + lg*4] = st4;
                        }
                        t += 8;
                    }
                    __syncthreads();                               // B5

                    // reduce + RK advance
                    {
                        float d0v = S.rowp[0][r0] + S.rowp[1][r0];
                        float d1v = S.rowp[0][r1] + S.rowp[1][r1];
                        float dxv = S.rowp[0][rx] + S.rowp[1][rx];
                        float v0 = tanh_fast(d0v + fb_r0) * S.xd[l16];
                        float v1 = tanh_fast(d1v + fb_r1) * S.xd[16 + l16];
                        float t2 = v0 + v1;
                        t2 += __shfl_xor(t2, 1);
                        t2 += __shfl_xor(t2, 2);
                        t2 += __shfl_xor(t2, 4);
                        t2 += __shfl_xor(t2, 8);        // sum over 32 rows
                        float ksum = t2 + tanh_fast(dxv + fb_rx) * S.xd[32];
                        if (l16 == 0) {
                            float yg = S.y[g16];
                            if (st == 0)      { ka = ksum;  S.yt[g16] = yg + 0.5f*hs*ksum; }
                            else if (st == 1) { kb2 = ksum; S.yt[g16] = yg + 0.5f*hs*ksum; }
                            else if (st == 2) { kc = ksum;  S.yt[g16] = yg + hs*ksum; }
                            else S.y[g16] = yg + hs*(1.f/6.f)*(ka + 2.f*kb2 + 2.f*kc + ksum);
                        }
                    }
                } else {
                    // fallback: unpack h to f32, VALU output (correct path)
                    if (tid < 64) {
                        unsigned int uh = S.hpk[1][0][tid], ul = S.hpk[1][1][tid];
                        S.rowp[0][2*tid]   = b2f_lo(uh) + b2f_lo(ul);
                        S.rowp[0][2*tid+1] = b2f_hi(uh) + b2f_hi(ul);
                    }
                    __syncthreads();
                    const float* hin = S.rowp[0];
                    float a0 = 0.f, a1 = 0.f, ax = 0.f;
                    #pragma unroll 2
                    for (int j = 0; j < 16; ++j) {
                        const float4* h4 = (const float4*)(hin + j*8);
                        float4 ha = h4[0], hb2 = h4[1];
                        float w8[8];
                        P::ld8(fWo, r0*WID + j*8, w8);
                        a0 += w8[0]*ha.x + w8[1]*ha.y + w8[2]*ha.z + w8[3]*ha.w
                            + w8[4]*hb2.x + w8[5]*hb2.y + w8[6]*hb2.z + w8[7]*hb2.w;
                        P::ld8(fWo, r1*WID + j*8, w8);
                        a1 += w8[0]*ha.x + w8[1]*ha.y + w8[2]*ha.z + w8[3]*ha.w
                            + w8[4]*hb2.x + w8[5]*hb2.y + w8[6]*hb2.z + w8[7]*hb2.w;
                    }
                    {
                        float w8[8];
                        P::ld8(fWo, rx*WID + l16*8, w8);
                        const float4* h4 = (const float4*)(hin + l16*8);
                        float4 ha = h4[0], hb2 = h4[1];
                        ax = w8[0]*ha.x + w8[1]*ha.y + w8[2]*ha.z + w8[3]*ha.w
                           + w8[4]*hb2.x + w8[5]*hb2.y + w8[6]*hb2.z + w8[7]*hb2.w;
                    }
                    ax += __shfl_xor(ax, 1);
                    ax += __shfl_xor(ax, 2);
                    ax += __shfl_xor(ax, 4);
                    ax += __shfl_xor(ax, 8);
                    float v0 = tanh_fast(a0 + fb_r0) * S.xd[l16];
                    float v1 = tanh_fast(a1 + fb_r1) * S.xd[16 + l16];
                    float t2 = v0 + v1;
                    t2 += __shfl_xor(t2, 1);
                    t2 += __shfl_xor(t2, 2);
                    t2 += __shfl_xor(t2, 4);
                    t2 += __shfl_xor(t2, 8);
                    float ksum = t2 + tanh_fast(ax + fb_rx) * S.xd[32];
                    if (l16 == 0) {
                        float yg = S.y[g16];
                        if (st == 0)      { ka = ksum;  S.yt[g16] = yg + 0.5f*hs*ksum; }
                        else if (st == 1) { kb2 = ksum; S.yt[g16] = yg + 0.5f*hs*ksum; }
                        else if (st == 2) { kc = ksum;  S.yt[g16] = yg + hs*ksum; }
                        else S.y[g16] = yg + hs*(1.f/6.f)*(ka + 2.f*kb2 + 2.f*kc + ksum);
                    }
                }
                __syncthreads();                                   // B_end
            }
        }

        if (tid < OUTD) {
            float a = P::ld(lb, tid);
            #pragma unroll 8
            for (int k2 = 0; k2 < HID; ++k2) a += S.lWt[k2*OUTD + tid] * S.y[k2];
            P::st(out, b*T_N*OUTD + (iv+1)*OUTD + tid, a);
        }
    }
}

__global__ __launch_bounds__(NTH)
void cde_kernel(const void* ts, const void* ys, const void* iW0, const void* ib0,
                const void* iWh, const void* ibh, const void* iWo, const void* ibo,
                const void* fW0, const void* fb0, const void* fWh, const void* fbh,
                const void* fWo, const void* fbo, const void* lW, const void* lb,
                const unsigned short* ws, int use_ws, void* out)
{
    __shared__ Smem S;
    const bool isbf = (((const unsigned short*)ts)[1] == 0x3C00);
    if (use_ws) {
        if (isbf)
            run_cde<PolBF16, true>(ts, ys, iW0, ib0, iWh, ibh, iWo, ibo,
                                   fW0, fb0, fWh, fbh, fWo, fbo, lW, lb,
                                   ws, out, S);
        else
            run_cde<PolF32, true>(ts, ys, iW0, ib0, iWh, ibh, iWo, ibo,
                                  fW0, fb0, fWh, fbh, fWo, fbo, lW, lb,
                                  ws, out, S);
    } else {
        if (isbf)
            run_cde<PolBF16, false>(ts, ys, iW0, ib0, iWh, ibh, iWo, ibo,
                                    fW0, fb0, fWh, fbh, fWo, fbo, lW, lb,
                                    fWo, out, S);
        else
            run_cde<PolF32, false>(ts, ys, iW0, ib0, iWh, ibh, iWo, ibo,
                                   fW0, fb0, fWh, fbh, fWo, fbo, lW, lb,
                                   fWo, out, S);
    }
}

extern "C" void kernel_launch(void* const* d_in, const int* in_sizes, int n_in,
                              void* d_out, int out_size, void* d_ws, size_t ws_size,
                              hipStream_t stream) {
    (void)in_sizes; (void)n_in; (void)out_size;
    const int use_ws = (ws_size >= WS_NEED) ? 1 : 0;
    if (use_ws) {
        const int nprep = (NPLANES * 64) / NTH;   // 33 blocks
        hipLaunchKernelGGL(prep_kernel, dim3(nprep), dim3(NTH), 0, stream,
                           d_in[0], d_in[12], (unsigned short*)d_ws);
    }
    hipLaunchKernelGGL(cde_kernel, dim3(B_N), dim3(NTH), 0, stream,
                       d_in[0], d_in[1], d_in[2], d_in[3], d_in[4], d_in[5],
                       d_in[6], d_in[7], d_in[8], d_in[9], d_in[10], d_in[11],
                       d_in[12], d_in[13], d_in[14], d_in[15],
                       (const unsigned short*)d_ws, use_ws, d_out);
}

// Round 13
// 13340.419 us; speedup vs baseline: 2.6196x; 2.6196x over previous
//
#include <hip/hip_runtime.h>
#include <stdint.h>

#define T_N   128
#define B_N   64
#define OBS   32
#define C_N   33      // OBS+1
#define HID   64
#define WID   128
#define FOUT  2112    // HID*C_N
#define OUTD  32
#define NSUB  4
#define NTH   1024

// d_ws: 32 planes of [NTH][8 bf16] = coalesced load-order copy of fWo rows
// r0(tid), r1(tid);  plane p = 2*j + half   (round-4 proven layout)
#define WS_PLANES 32
#define PLB       (NTH * 16)
#define WS_NEED   ((size_t)WS_PLANES * PLB)   // 512 KB

typedef __attribute__((ext_vector_type(2))) float f32x2;

__device__ __forceinline__ float b2f(unsigned short u) {
    return __uint_as_float(((unsigned int)u) << 16);
}
__device__ __forceinline__ float b2f_lo(unsigned int u) {
    return __uint_as_float(u << 16);
}
__device__ __forceinline__ float b2f_hi(unsigned int u) {
    return __uint_as_float(u & 0xffff0000u);
}
__device__ __forceinline__ unsigned short f2b(float f) {
    unsigned int u = __float_as_uint(f);
    unsigned int lsb = (u >> 16) & 1u;
    u += 0x7fffu + lsb;   // round to nearest even
    return (unsigned short)(u >> 16);
}
__device__ __forceinline__ unsigned int pack2(float a, float b) {
    return ((unsigned int)f2b(a)) | (((unsigned int)f2b(b)) << 16);
}
__device__ __forceinline__ float softplus_f(float x) {
    return fmaxf(x, 0.f) + __logf(1.f + __expf(-fabsf(x)));
}
__device__ __forceinline__ float tanh_fast(float x) {
    float e = __expf(2.f * x);
    return 1.f - 2.f / (e + 1.f);
}
// bf16 pair -> f32x2 (targets v_pk_fma_f32 consumption)
__device__ __forceinline__ f32x2 up2(unsigned int u) {
    f32x2 r; r.x = b2f_lo(u); r.y = b2f_hi(u); return r;
}
__device__ __forceinline__ f32x2 mk2(float a, float b) {
    f32x2 r; r.x = a; r.y = b; return r;
}

// ---- dtype policies -------------------------------------------------------
struct PolBF16 {
    static __device__ __forceinline__ float ld(const void* p, int i) {
        return b2f(((const unsigned short*)p)[i]);
    }
    static __device__ __forceinline__ void ld8(const void* p, int i, float* o) {
        uint4 u = *(const uint4*)((const unsigned short*)p + i);
        o[0]=b2f_lo(u.x); o[1]=b2f_hi(u.x); o[2]=b2f_lo(u.y); o[3]=b2f_hi(u.y);
        o[4]=b2f_lo(u.z); o[5]=b2f_hi(u.z); o[6]=b2f_lo(u.w); o[7]=b2f_hi(u.w);
    }
    static __device__ __forceinline__ void st(void* p, int i, float v) {
        ((unsigned short*)p)[i] = f2b(v);
    }
};
struct PolF32 {
    static __device__ __forceinline__ float ld(const void* p, int i) {
        return ((const float*)p)[i];
    }
    static __device__ __forceinline__ void ld8(const void* p, int i, float* o) {
        const float4* q = (const float4*)((const float*)p + i);
        float4 a = q[0], b = q[1];
        o[0]=a.x; o[1]=a.y; o[2]=a.z; o[3]=a.w;
        o[4]=b.x; o[5]=b.y; o[6]=b.z; o[7]=b.w;
    }
    static __device__ __forceinline__ void st(void* p, int i, float v) {
        ((float*)p)[i] = v;
    }
};

// LDS: hidden weights per-thread-keyed (16B lane stride) + activations
struct __align__(16) Smem {
    uint4 whv[3][2][NTH];            // 96 KB : hidden weights (bf16x8 chunks)
    float h[2][WID];                 // ping-pong hidden vector
    float y[HID];
    float yt[HID];
    float xd[C_N], d0[C_N], cc[C_N], bb[C_N];
    float fb0[WID];
    float fbh[3][WID];
    float lWt[HID*OUTD];             // transposed [k][o]
};  // ~108 KB (1 block/CU)

// ---- weight prep: fWo -> coalesced bf16 planes in d_ws --------------------
template<class P>
__device__ __forceinline__ void prep_body(const void* fWo, unsigned short* ws) {
    const int bid = blockIdx.x;          // 0..31
    const int tid = threadIdx.x;
    const int j    = bid >> 1;
    const int half = bid & 1;
    const int row  = (tid >> 4) * C_N + (tid & 15) + (half ? 16 : 0);
    float v[8];
    P::ld8(fWo, row*WID + j*8, v);
    uint4 u;
    u.x = pack2(v[0], v[1]); u.y = pack2(v[2], v[3]);
    u.z = pack2(v[4], v[5]); u.w = pack2(v[6], v[7]);
    ((uint4*)ws)[bid*NTH + tid] = u;
}
__global__ __launch_bounds__(NTH)
void prep_kernel(const void* ts, const void* fWo, unsigned short* ws) {
    const bool isbf = (((const unsigned short*)ts)[1] == 0x3C00);
    if (isbf) prep_body<PolBF16>(fWo, ws);
    else      prep_body<PolF32>(fWo, ws);
}

// ---- main persistent-per-batch kernel -------------------------------------
template<class P, bool COAL>
__device__ void run_cde(
    const void* ts, const void* ys, const void* iW0, const void* ib0,
    const void* iWh, const void* ibh, const void* iWo, const void* ibo,
    const void* fW0, const void* fb0, const void* fWh, const void* fbh,
    const void* fWo, const void* fbo, const void* lW, const void* lb,
    const void* wWo, void* out, Smem& S)
{
    const int tid  = threadIdx.x;
    const int b    = blockIdx.x;
    const int row8 = tid >> 3;       // 0..127 : layer0/hidden row
    const int seg8 = tid & 7;        // 0..7   : K-segment
    const int rot8 = seg8 >> 1;      // bank-decorrelating traversal rotation
    const int g16  = tid >> 4;       // 0..63  : output group == h index
    const int l16  = tid & 15;       // 0..15  : lane within group
    const int r0   = g16*C_N + l16;        // output row (c = l16)
    const int r1   = r0 + 16;              // output row (c = 16+l16)
    const int rx   = g16*C_N + 32;         // shared row (c = 32)

    // ---- small per-thread weights in REGISTERS (8 VGPRs, static) ----
    uint4 w0v;
    {   // layer0: fW0 is [WID][HID]; this thread: row row8, k = seg8*8..+7
        const int kb = row8*HID + seg8*8;
        w0v.x = pack2(P::ld(fW0, kb+0), P::ld(fW0, kb+1));
        w0v.y = pack2(P::ld(fW0, kb+2), P::ld(fW0, kb+3));
        w0v.z = pack2(P::ld(fW0, kb+4), P::ld(fW0, kb+5));
        w0v.w = pack2(P::ld(fW0, kb+6), P::ld(fW0, kb+7));
    }
    uint4 wxv;
    {   // shared output row (c==32): this lane's K-segment k=l16*8..+7
        const int kb = rx*WID + l16*8;
        wxv.x = pack2(P::ld(fWo, kb+0), P::ld(fWo, kb+1));
        wxv.y = pack2(P::ld(fWo, kb+2), P::ld(fWo, kb+3));
        wxv.z = pack2(P::ld(fWo, kb+4), P::ld(fWo, kb+5));
        wxv.w = pack2(P::ld(fWo, kb+6), P::ld(fWo, kb+7));
    }

    // ---- hidden weights into LDS (rot8-rotated traversal order) ----
    #pragma unroll
    for (int l = 0; l < 3; ++l) {
        #pragma unroll
        for (int c = 0; c < 2; ++c) {
            const int j0 = (c*2 + 0 + rot8) & 3;
            const int j1 = (c*2 + 1 + rot8) & 3;
            const int k0 = (l*WID + row8)*WID + seg8*16 + j0*4;
            const int k1 = (l*WID + row8)*WID + seg8*16 + j1*4;
            uint4 u;
            u.x = pack2(P::ld(fWh, k0+0), P::ld(fWh, k0+1));
            u.y = pack2(P::ld(fWh, k0+2), P::ld(fWh, k0+3));
            u.z = pack2(P::ld(fWh, k1+0), P::ld(fWh, k1+1));
            u.w = pack2(P::ld(fWh, k1+2), P::ld(fWh, k1+3));
            S.whv[l][c][tid] = u;
        }
    }

    const float fb_r0 = P::ld(fbo, r0);
    const float fb_r1 = P::ld(fbo, r1);
    const float fb_rx = P::ld(fbo, rx);

    // ---- constants to LDS ----
    if (tid < WID)  S.fb0[tid] = P::ld(fb0, tid);
    if (tid < 3*WID) S.fbh[tid>>7][tid&127] = P::ld(fbh, tid);
    for (int i = tid; i < OUTD*HID; i += NTH) {
        int o = i >> 6, kk = i & 63;             // lW is [o][k]
        S.lWt[kk*OUTD + o] = P::ld(lW, i);
    }
    if (tid < C_N)
        S.xd[tid] = (tid == 0) ? P::ld(ts, 0) : P::ld(ys, b*T_N*OBS + (tid-1));
    __syncthreads();

    // ---- initial MLP (relu hidden, identity out) -> y0 (runs once) ----
    if (tid < WID) {
        float a = P::ld(ib0, tid);
        for (int k2 = 0; k2 < C_N; ++k2) a += P::ld(iW0, tid*C_N + k2) * S.xd[k2];
        S.h[0][tid] = fmaxf(a, 0.f);
    }
    __syncthreads();
    int pp = 0;
    for (int l = 0; l < 3; ++l) {
        if (tid < WID) {
            float a = P::ld(ibh, l*WID + tid);
            for (int k2 = 0; k2 < WID; ++k2)
                a += P::ld(iWh, (l*WID + tid)*WID + k2) * S.h[pp][k2];
            S.h[1-pp][tid] = fmaxf(a, 0.f);
        }
        __syncthreads();
        pp ^= 1;
    }
    if (tid < HID) {
        float a = P::ld(ibo, tid);
        for (int k2 = 0; k2 < WID; ++k2)
            a += P::ld(iWo, tid*WID + k2) * S.h[pp][k2];
        S.y[tid] = a;
    }
    __syncthreads();
    if (tid < OUTD) {
        float a = P::ld(lb, tid);
        for (int k2 = 0; k2 < HID; ++k2) a += S.lWt[k2*OUTD + tid] * S.y[k2];
        P::st(out, b*T_N*OUTD + tid, a);
    }

    // ---- sequential intervals ----
    #pragma unroll 1
    for (int iv = 0; iv < T_N-1; ++iv) {
        float t0 = P::ld(ts, iv), t1 = P::ld(ts, iv+1);
        float dt = t1 - t0;
        float hs = dt * (1.f/NSUB);
        if (tid < C_N) {
            float v0 = (tid==0) ? t0 : P::ld(ys, b*T_N*OBS + iv*OBS + (tid-1));
            float v1 = (tid==0) ? t1 : P::ld(ys, b*T_N*OBS + (iv+1)*OBS + (tid-1));
            float di = (v1 - v0) / dt;
            float d0v;
            if (iv == 0) d0v = di;
            else {
                float tm = P::ld(ts, iv-1);
                float vm = (tid==0) ? tm : P::ld(ys, b*T_N*OBS + (iv-1)*OBS + (tid-1));
                d0v = (v0 - vm) / (t0 - tm);
            }
            float d1v = di;
            S.d0[tid] = d0v;
            S.cc[tid] = (3.f*di - 2.f*d0v - d1v) / dt;
            S.bb[tid] = (d0v + d1v - 2.f*di) / (dt*dt);
        }
        __syncthreads();

        #pragma unroll 1
        for (int sub = 0; sub < NSUB; ++sub) {
            float s0 = sub * hs;
            float ka = 0.f, kb = 0.f, kc = 0.f;      // RK stage sums (l16==0)
            #pragma unroll 1
            for (int st = 0; st < 4; ++st) {
                float s = (st==0) ? s0 : ((st==3) ? s0+hs : s0 + 0.5f*hs);
                const float* yin = (st==0) ? S.y : S.yt;

                // xdot(s) (threads 0..32, overlapped with layer0)
                if (tid < C_N)
                    S.xd[tid] = S.d0[tid] + (2.f*S.cc[tid] + 3.f*S.bb[tid]*s)*s;

                // ---- layer 0: 128 rows x 8 K-segs of 8, w0v in regs ----
                {
                    const float4* y4 = (const float4*)(yin + seg8*8);
                    float4 ya = y4[0], yb = y4[1];
                    f32x2 av = {0.f, 0.f};
                    av += up2(w0v.x) * mk2(ya.x, ya.y);
                    av += up2(w0v.y) * mk2(ya.z, ya.w);
                    av += up2(w0v.z) * mk2(yb.x, yb.y);
                    av += up2(w0v.w) * mk2(yb.z, yb.w);
                    float a = av.x + av.y;
                    a += __shfl_xor(a, 1);
                    a += __shfl_xor(a, 2);
                    a += __shfl_xor(a, 4);
                    if (seg8 == 0) S.h[0][row8] = softplus_f(a + S.fb0[row8]);
                }
                __syncthreads();                                   // B1

                // ---- 3 hidden layers: weights from LDS (b128), packed ----
                #pragma unroll
                for (int l = 0; l < 3; ++l) {
                    const int hp = l & 1;
                    const float* hb = S.h[hp] + seg8*16;
                    uint4 wa = S.whv[l][0][tid];
                    uint4 wb = S.whv[l][1][tid];
                    f32x2 av = {0.f, 0.f};
                    { int j=(0+rot8)&3; float4 hv=*(const float4*)(hb+j*4);
                      av += up2(wa.x)*mk2(hv.x,hv.y);
                      av += up2(wa.y)*mk2(hv.z,hv.w); }
                    { int j=(1+rot8)&3; float4 hv=*(const float4*)(hb+j*4);
                      av += up2(wa.z)*mk2(hv.x,hv.y);
                      av += up2(wa.w)*mk2(hv.z,hv.w); }
                    { int j=(2+rot8)&3; float4 hv=*(const float4*)(hb+j*4);
                      av += up2(wb.x)*mk2(hv.x,hv.y);
                      av += up2(wb.y)*mk2(hv.z,hv.w); }
                    { int j=(3+rot8)&3; float4 hv=*(const float4*)(hb+j*4);
                      av += up2(wb.z)*mk2(hv.x,hv.y);
                      av += up2(wb.w)*mk2(hv.z,hv.w); }
                    float a = av.x + av.y;
                    a += __shfl_xor(a, 1);
                    a += __shfl_xor(a, 2);
                    a += __shfl_xor(a, 4);
                    if (seg8 == 0) S.h[1-hp][row8] = softplus_f(a + S.fbh[l][row8]);
                    __syncthreads();                               // B2..B4
                }

                // ---- output layer + k-reduce + RK advance (one phase) ----
                {
                    const float* hin = S.h[1];          // after 3 layers
                    // shared row (c==32) from regs
                    f32x2 AX = {0.f, 0.f};
                    {
                        const float4* h4 = (const float4*)(hin + l16*8);
                        float4 ha = h4[0], hb2 = h4[1];
                        AX += up2(wxv.x) * mk2(ha.x, ha.y);
                        AX += up2(wxv.y) * mk2(ha.z, ha.w);
                        AX += up2(wxv.z) * mk2(hb2.x, hb2.y);
                        AX += up2(wxv.w) * mk2(hb2.z, hb2.w);
                    }
                    f32x2 A0 = {0.f, 0.f}, A1 = {0.f, 0.f};
                    if constexpr (COAL) {
                        const uint4* wp = (const uint4*)wWo + tid;
                        #pragma unroll 4
                        for (int j = 0; j < 16; ++j) {
                            const float4* h4 = (const float4*)(hin + j*8);
                            float4 ha = h4[0], hb2 = h4[1];
                            uint4 u0 = wp[(2*j+0)*NTH];
                            uint4 u1 = wp[(2*j+1)*NTH];
                            f32x2 h01 = mk2(ha.x, ha.y),  h23 = mk2(ha.z, ha.w);
                            f32x2 h45 = mk2(hb2.x,hb2.y), h67 = mk2(hb2.z,hb2.w);
                            A0 += up2(u0.x)*h01; A0 += up2(u0.y)*h23;
                            A0 += up2(u0.z)*h45; A0 += up2(u0.w)*h67;
                            A1 += up2(u1.x)*h01; A1 += up2(u1.y)*h23;
                            A1 += up2(u1.z)*h45; A1 += up2(u1.w)*h67;
                        }
                    } else {
                        #pragma unroll 4
                        for (int j = 0; j < 16; ++j) {
                            const float4* h4 = (const float4*)(hin + j*8);
                            float4 ha = h4[0], hb2 = h4[1];
                            float w8[8];
                            f32x2 h01 = mk2(ha.x, ha.y),  h23 = mk2(ha.z, ha.w);
                            f32x2 h45 = mk2(hb2.x,hb2.y), h67 = mk2(hb2.z,hb2.w);
                            P::ld8(fWo, r0*WID + j*8, w8);
                            A0 += mk2(w8[0],w8[1])*h01; A0 += mk2(w8[2],w8[3])*h23;
                            A0 += mk2(w8[4],w8[5])*h45; A0 += mk2(w8[6],w8[7])*h67;
                            P::ld8(fWo, r1*WID + j*8, w8);
                            A1 += mk2(w8[0],w8[1])*h01; A1 += mk2(w8[2],w8[3])*h23;
                            A1 += mk2(w8[4],w8[5])*h45; A1 += mk2(w8[6],w8[7])*h67;
                        }
                    }
                    float a0 = A0.x + A0.y;
                    float a1 = A1.x + A1.y;
                    float ax = AX.x + AX.y;
                    ax += __shfl_xor(ax, 1);
                    ax += __shfl_xor(ax, 2);
                    ax += __shfl_xor(ax, 4);
                    ax += __shfl_xor(ax, 8);            // full K-sum of row rx

                    float v0 = tanh_fast(a0 + fb_r0) * S.xd[l16];
                    float v1 = tanh_fast(a1 + fb_r1) * S.xd[16 + l16];
                    float t2 = v0 + v1;
                    t2 += __shfl_xor(t2, 1);
                    t2 += __shfl_xor(t2, 2);
                    t2 += __shfl_xor(t2, 4);
                    t2 += __shfl_xor(t2, 8);            // sum over 32 rows
                    float ksum = t2 + tanh_fast(ax + fb_rx) * S.xd[32];

                    if (l16 == 0) {
                        float yg = S.y[g16];
                        if (st == 0)      { ka = ksum; S.yt[g16] = yg + 0.5f*hs*ksum; }
                        else if (st == 1) { kb = ksum; S.yt[g16] = yg + 0.5f*hs*ksum; }
                        else if (st == 2) { kc = ksum; S.yt[g16] = yg + hs*ksum; }
                        else S.y[g16] = yg + hs*(1.f/6.f)*(ka + 2.f*kb + 2.f*kc + ksum);
                    }
                }
                __syncthreads();                                   // B5
            }
        }

        if (tid < OUTD) {
            float a = P::ld(lb, tid);
            #pragma unroll 8
            for (int k2 = 0; k2 < HID; ++k2) a += S.lWt[k2*OUTD + tid] * S.y[k2];
            P::st(out, b*T_N*OUTD + (iv+1)*OUTD + tid, a);
        }
    }
}

__global__ __launch_bounds__(NTH)
void cde_kernel(const void* ts, const void* ys, const void* iW0, const void* ib0,
                const void* iWh, const void* ibh, const void* iWo, const void* ibo,
                const void* fW0, const void* fb0, const void* fWh, const void* fbh,
                const void* fWo, const void* fbo, const void* lW, const void* lb,
                const unsigned short* ws, int use_ws, void* out)
{
    __shared__ Smem S;
    const bool isbf = (((const unsigned short*)ts)[1] == 0x3C00);
    if (use_ws) {
        if (isbf)
            run_cde<PolBF16, true>(ts, ys, iW0, ib0, iWh, ibh, iWo, ibo,
                                   fW0, fb0, fWh, fbh, fWo, fbo, lW, lb,
                                   ws, out, S);
        else
            run_cde<PolF32, true>(ts, ys, iW0, ib0, iWh, ibh, iWo, ibo,
                                  fW0, fb0, fWh, fbh, fWo, fbo, lW, lb,
                                  ws, out, S);
    } else {
        if (isbf)
            run_cde<PolBF16, false>(ts, ys, iW0, ib0, iWh, ibh, iWo, ibo,
                                    fW0, fb0, fWh, fbh, fWo, fbo, lW, lb,
                                    fWo, out, S);
        else
            run_cde<PolF32, false>(ts, ys, iW0, ib0, iWh, ibh, iWo, ibo,
                                   fW0, fb0, fWh, fbh, fWo, fbo, lW, lb,
                                   fWo, out, S);
    }
}

extern "C" void kernel_launch(void* const* d_in, const int* in_sizes, int n_in,
                              void* d_out, int out_size, void* d_ws, size_t ws_size,
                              hipStream_t stream) {
    (void)in_sizes; (void)n_in; (void)out_size;
    const int use_ws = (ws_size >= WS_NEED) ? 1 : 0;
    if (use_ws) {
        hipLaunchKernelGGL(prep_kernel, dim3(WS_PLANES), dim3(NTH), 0, stream,
                           d_in[0], d_in[12], (unsigned short*)d_ws);
    }
    hipLaunchKernelGGL(cde_kernel, dim3(B_N), dim3(NTH), 0, stream,
                       d_in[0], d_in[1], d_in[2], d_in[3], d_in[4], d_in[5],
                       d_in[6], d_in[7], d_in[8], d_in[9], d_in[10], d_in[11],
                       d_in[12], d_in[13], d_in[14], d_in[15],
                       (const unsigned short*)d_ws, use_ws, d_out);
}